// Round 3
// baseline (667.118 us; speedup 1.0000x reference)
//
#include <hip/hip_runtime.h>

#define NPTS   21
#define BATCH  16384
#define ROWS   (BATCH * NPTS)            // 344064 flat (b*21+n) rows
#define NGRP   ((BATCH + 2) / 3)         // 5462 groups of 3 batch elems (63 rows -> pad 64)
#define GPB    2
#define NBLK   ((NGRP + GPB - 1) / GPB)  // 2731 blocks
#define YSTR   200                       // Yt row stride in u16: 100 dw (%32=4, banks ok), %8=0 (16B align)

typedef unsigned short u16;
typedef unsigned int   u32;
typedef __bf16 bf16x8 __attribute__((ext_vector_type(8)));
typedef u16    u16x8  __attribute__((ext_vector_type(8)));
typedef float  f32x4  __attribute__((ext_vector_type(4)));

static __device__ __forceinline__ u16 f2bf(float f) {
  union { float f; u32 u; } v; v.f = f;
  u32 r = v.u + 0x7fffu + ((v.u >> 16) & 1u);   // RNE
  return (u16)(r >> 16);
}
static __device__ __forceinline__ u32 pk2(float a, float b) {
  return (u32)f2bf(a) | ((u32)f2bf(b) << 16);   // low 16 = a, high 16 = b
}

// ---- prep: bf16 weights (d-major) + mixing matrix Mbig[64][192] ------------
__global__ void cheb_prep(const float* __restrict__ adj,
                          const float* __restrict__ weight,   // [3][1][128][128]
                          u16* __restrict__ WtG,              // [128][384]: Wt[d][k*128+c]
                          u16* __restrict__ MbG) {            // [64][192]:  Mbig[r][k*64+m]
  const int tid = threadIdx.x;
  if (blockIdx.x < 64) {
    int gid = blockIdx.x * 256 + tid;
    for (int idx = gid; idx < 128 * 384; idx += 64 * 256) {
      int d = idx / 384, kc = idx - d * 384;
      WtG[idx] = f2bf(weight[kc * 128 + d]);
    }
  } else {
    __shared__ float Ls[441], T2s[441], dsi[21];
    if (tid < 21) {
      float s = 0.f;
      for (int m = 0; m < 21; ++m) s += adj[tid * 21 + m];
      dsi[tid] = (s > 0.f) ? (1.0f / sqrtf(s)) : 0.f;
    }
    __syncthreads();
    for (int i = tid; i < 441; i += 256) {
      int n = i / 21, m = i - n * 21;
      Ls[i] = ((n == m) ? 1.f : 0.f) - dsi[n] * adj[i] * dsi[m];
    }
    __syncthreads();
    for (int i = tid; i < 441; i += 256) {
      int n = i / 21, m = i - n * 21;
      float s = 0.f;
      for (int j = 0; j < 21; ++j) s += Ls[n * 21 + j] * Ls[j * 21 + m];
      T2s[i] = 2.f * s - ((n == m) ? 1.f : 0.f);
    }
    __syncthreads();
    for (int idx = tid; idx < 64 * 192; idx += 256) {
      int r = idx / 192, km = idx - r * 192;
      int k = km >> 6, mw = km & 63;
      float v = 0.f;
      if (r < 63) {
        int lb = r / 21, n = r - lb * 21;
        int mm = mw - lb * 21;
        if (mm >= 0 && mm < 21)
          v = (k == 0) ? ((n == mm) ? 1.f : 0.f)
                       : ((k == 1) ? Ls[n * 21 + mm] : T2s[n * 21 + mm]);
      }
      MbG[idx] = f2bf(v);
    }
  }
}

// ---- main: stage1 Y_k = X W_k (MFMA) -> LDS; stage2 out = Mbig x Y (MFMA) --
__global__ void __launch_bounds__(256, 3) cheb_main(
    const float* __restrict__ x,      // [344064][128] fp32 (rows = b*21+n)
    const u16*  __restrict__ WtG,     // [128][384]
    const u16*  __restrict__ MbG,     // [64][192]
    const float* __restrict__ bias,   // [128]
    float* __restrict__ out) {        // [344064][128] fp32
  __shared__ u16 Yt[128 * YSTR];      // Yt[d][km], km = k*64 + m-row, bf16

  const int tid  = threadIdx.x;
  const int wave = tid >> 6;
  const int lane = tid & 63;
  const int quad = lane >> 4;
  const int l15  = lane & 15;

  // resident stage-1 B frags: wave owns d-cols [wave*32, wave*32+32)
  // B[k=c][n=d] -> WtG[d][k*128 + ks*32 + quad*8 + j], 8 contiguous
  u16x8 Breg[3][2][4];                // 96 VGPR
#pragma unroll
  for (int k = 0; k < 3; ++k)
#pragma unroll
    for (int nt = 0; nt < 2; ++nt) {
      const u16* wp = WtG + (wave * 32 + nt * 16 + l15) * 384 + k * 128 + quad * 8;
#pragma unroll
      for (int ks = 0; ks < 4; ++ks) Breg[k][nt][ks] = *(const u16x8*)(wp + ks * 32);
    }
  // resident stage-2 B frags: wave owns out-rows r in [wave*16, wave*16+16)
  // B[km][r] = Mbig[r][km], 8 contiguous km per lane
  u16x8 Mreg[6];                      // 24 VGPR
  {
    const u16* mp = MbG + (wave * 16 + l15) * 192 + quad * 8;
#pragma unroll
    for (int ks = 0; ks < 6; ++ks) Mreg[ks] = *(const u16x8*)(mp + ks * 32);
  }

  for (int it = 0; it < GPB; ++it) {
    const int grp = blockIdx.x * GPB + it;
    if (grp >= NGRP) break;                    // uniform
    const long gr0 = (long)grp * 63;

    // ---- stage 1: Y_k[m][d] = sum_c X[m][c] Wk[c][d], D -> Yt[d][k*64+m] ----
#pragma unroll 1
    for (int mt = 0; mt < 4; ++mt) {
      long gr = gr0 + mt * 16 + l15;
      if (gr > (long)ROWS - 1) gr = ROWS - 1;  // clamp (garbage rows masked by Mbig zeros)
      const float* xp = x + gr * 128 + quad * 8;
      u16x8 A[4];
#pragma unroll
      for (int ks = 0; ks < 4; ++ks) {
        float4 f0 = *(const float4*)(xp + ks * 32);
        float4 f1 = *(const float4*)(xp + ks * 32 + 4);
        union { u32 w[4]; u16x8 v; } u;
        u.w[0] = pk2(f0.x, f0.y); u.w[1] = pk2(f0.z, f0.w);
        u.w[2] = pk2(f1.x, f1.y); u.w[3] = pk2(f1.z, f1.w);
        A[ks] = u.v;
      }
#pragma unroll 1
      for (int k = 0; k < 3; ++k) {
#pragma unroll
        for (int nt = 0; nt < 2; ++nt) {
          f32x4 acc = {0.f, 0.f, 0.f, 0.f};
#pragma unroll
          for (int ks = 0; ks < 4; ++ks)
            acc = __builtin_amdgcn_mfma_f32_16x16x32_bf16(
                __builtin_bit_cast(bf16x8, A[ks]),
                __builtin_bit_cast(bf16x8, Breg[k][nt][ks]), acc, 0, 0, 0);
          // D: m-row = mt*16 + quad*4 + i, d-col = wave*32 + nt*16 + l15
          int d = wave * 32 + nt * 16 + l15;
          u32 lo = pk2(acc[0], acc[1]);
          u32 hi = pk2(acc[2], acc[3]);
          *(uint2*)(&Yt[d * YSTR + k * 64 + mt * 16 + quad * 4]) = make_uint2(lo, hi);
        }
      }
    }
    __syncthreads();

    // ---- stage 2: out^T[d][r] = sum_km Yt[d][km] * Mbig[r][km] ----
    const int r  = wave * 16 + l15;            // this lane's out-row (n-dim)
    const long gr = gr0 + r;
    const bool wr = (r < 63) && (gr < (long)ROWS);
#pragma unroll 1
    for (int mt = 0; mt < 8; ++mt) {
      const u16* yp = &Yt[(mt * 16 + l15) * YSTR + quad * 8];
      f32x4 acc = {0.f, 0.f, 0.f, 0.f};
#pragma unroll
      for (int ks = 0; ks < 6; ++ks)
        acc = __builtin_amdgcn_mfma_f32_16x16x32_bf16(
            *(const bf16x8*)(yp + ks * 32),
            __builtin_bit_cast(bf16x8, Mreg[ks]), acc, 0, 0, 0);
      if (wr) {
        // D: d = mt*16 + quad*4 + i (4 consecutive), col = l15 -> row r
        int d0 = mt * 16 + quad * 4;
        float4 b = *(const float4*)(bias + d0);
        float4 o;
        o.x = acc[0] + b.x; o.y = acc[1] + b.y;
        o.z = acc[2] + b.z; o.w = acc[3] + b.w;
        *(float4*)(out + gr * 128 + d0) = o;
      }
    }
    __syncthreads();                           // Yt safe before next group's writes
  }
}

extern "C" void kernel_launch(void* const* d_in, const int* in_sizes, int n_in,
                              void* d_out, int out_size, void* d_ws, size_t ws_size,
                              hipStream_t stream) {
  (void)in_sizes; (void)n_in; (void)out_size; (void)ws_size;
  const float* x      = (const float*)d_in[0];
  const float* adj    = (const float*)d_in[1];
  const float* weight = (const float*)d_in[2];
  const float* bias   = (const float*)d_in[3];
  float* out = (float*)d_out;
  u16* WtG = (u16*)d_ws;                        // 96 KB
  u16* MbG = (u16*)((char*)d_ws + 98304);       // 24 KB
  cheb_prep<<<65, 256, 0, stream>>>(adj, weight, WtG, MbG);
  cheb_main<<<NBLK, 256, 0, stream>>>(x, WtG, MbG, bias, out);
}